// Round 12
// baseline (433.232 us; speedup 1.0000x reference)
//
#include <hip/hip_runtime.h>
#include <stdint.h>

// Problem constants
#define MROWS 32768      // B*S = 8*4096
#define KD    256        // 2*DIM
#define VOCABN 8192

typedef _Float16 half8  __attribute__((ext_vector_type(8)));
typedef _Float16 half4v __attribute__((ext_vector_type(4)));
typedef float  floatx4  __attribute__((ext_vector_type(4)));

// scratch layout (byte offsets within d_ws)
#define B_OFF     16777216u   // f16 cb [8192][256]   =  4,194,304 B
#define CN_OFF    20971520u   // f32 0.5*||c||^2 [8192] = 32,768 B
#define PART_OFF  21004288u   // float4 top2 [32768][8] = 4,194,304 B
#define IDX_OFF   25198592u   // int idx [32768] = 131,072 B
#define WS_NEED   25329664u

// ---- top-2 (max sigma) with smaller-index tie-break (merge/resolve path) ----
struct Top2 { float s1; int i1; float s2; int i2; };

__device__ __forceinline__ bool better(float sa, int ia, float sb, int ib) {
    return (sa > sb) || (sa == sb && ia < ib);
}
__device__ __forceinline__ Top2 merge2(const Top2& a, const Top2& b) {
    Top2 r;
    if (better(b.s1, b.i1, a.s1, a.i1)) {
        r.s1 = b.s1; r.i1 = b.i1;
        if (better(a.s1, a.i1, b.s2, b.i2)) { r.s2 = a.s1; r.i2 = a.i1; }
        else                                { r.s2 = b.s2; r.i2 = b.i2; }
    } else {
        r.s1 = a.s1; r.i1 = a.i1;
        if (better(b.s1, b.i1, a.s2, a.i2)) { r.s2 = b.s1; r.i2 = b.i1; }
        else                                { r.s2 = a.s2; r.i2 = a.i2; }
    }
    return r;
}

// monotone f32<->u32 order-preserving flip (for packed top-2)
__device__ __forceinline__ uint32_t fflip(uint32_t u) {
    return u ^ (0x80000000u | (uint32_t)((int32_t)u >> 31));
}
__device__ __forceinline__ uint32_t funflip(uint32_t v) {
    return v ^ (0x80000000u | (uint32_t)((int32_t)(~v) >> 31));
}
// sentinel: pack of (-3.4e38f, col10=1023) == 0x00800000
#define PACK_INIT 0x00800000u

// async global->LDS, 16 B per lane. LDS dest is WAVE-UNIFORM base + lane*16;
// global src is per-lane (swizzle is applied by pre-permuting the src).
__device__ __forceinline__ void gll16(const void* g, const void* l) {
    __builtin_amdgcn_global_load_lds(
        (const __attribute__((address_space(1))) void*)g,
        (__attribute__((address_space(3))) void*)l, 16, 0, 0);
}

// counted-vmcnt pipe barrier (T3/T4): drain to N outstanding, raw s_barrier.
#define PIPE_SYNC(N) do {                                        \
    asm volatile("s_waitcnt vmcnt(" #N ")" ::: "memory");        \
    __builtin_amdgcn_s_barrier();                                \
    __builtin_amdgcn_sched_barrier(0);                           \
} while (0)

// lgkm-only barrier (flush path): staged vmcnt loads stay in flight.
#define LGKM_BARRIER() do {                                      \
    asm volatile("s_waitcnt lgkmcnt(0)" ::: "memory");           \
    __builtin_amdgcn_s_barrier();                                \
    __builtin_amdgcn_sched_barrier(0);                           \
} while (0)

// ---- 1. codebook f16 [8192][256] + 0.5*||c||^2 fp32 (4 rows/block) ----
__global__ __launch_bounds__(256) void prep_c(const float* __restrict__ cb,
                                              _Float16* __restrict__ B,
                                              float* __restrict__ cnorm) {
    int v = blockIdx.x * 4 + (threadIdx.x >> 6);
    int lane = threadIdx.x & 63;               // 0..63, 4 floats each
    float4 c = ((const float4*)(cb + (size_t)v * 256))[lane];
    half4v h;
    h[0] = (_Float16)c.x; h[1] = (_Float16)c.y;
    h[2] = (_Float16)c.z; h[3] = (_Float16)c.w;
    ((half4v*)(B + (size_t)v * 256))[lane] = h;
    float s = c.x * c.x + c.y * c.y + c.z * c.z + c.w * c.w;
    #pragma unroll
    for (int m = 32; m; m >>= 1) s += __shfl_xor(s, m);
    if (lane == 0) cnorm[v] = 0.5f * s;
}

// ---- 2. f16 GEMM + per-row top-2 argmax(sigma) ----
// R26 post-mortem: launch_bounds(512,1) produced BYTE-IDENTICAL codegen to
// (512,2) -- VGPR 128, WRITE 59MB spills. The 2nd launch_bounds arg is only
// a MINIMUM waves/EU; the allocator's occupancy heuristic still CHOSE the
// 128-VGPR / 4-waves-per-EU point and paid 55MB/launch of in-loop scratch
// (its spill cost model is wrong here). R27 = R25 body, but the occupancy
// target is PINNED via amdgpu_waves_per_eu(2,2) (+ flat_work_group_size
// (512,512)): max=2 waves/EU -> 256-reg budget, no incentive to squeeze.
// Zero real cost: all 11 rounds measured ~8 waves/CU = 2 waves/SIMD anyway.
// Demand ~210 arch + 32 acc(AGPR) fits 256. Per-phase floor: 64 MFMA/SIMD
// x 19.4cy = 1242cy -> 128 phases ~ 67us + overhead.
__global__ void
__attribute__((amdgpu_flat_work_group_size(512, 512)))
__attribute__((amdgpu_waves_per_eu(2, 2)))
gemm_argmin(const float* __restrict__ gr,
            const float* __restrict__ gi,
            const _Float16* __restrict__ B,
            const float* __restrict__ cnorm,
            float4* __restrict__ part) {
    // LDS: 4 sets x 32 KB (4 sub-slices x 8 KB) | 8 KB topbuf = 136 KB
    __shared__ __align__(16) char lds[139264];
    float4* topbuf = (float4*)(lds + 131072);   // [128 rows][4 cg]

    const int tid = threadIdx.x;
    const int m0 = blockIdx.x * 128;            // grid 256
    const int wave = tid >> 6, lane = tid & 63;
    const int rg = wave >> 2, cg = wave & 3;    // 2 row-groups x 4 col-groups
    const int lane16 = lane & 15, quad = lane >> 4;

    // A-fragments: wave owns rows m0+rg*64+rt*16+lane16 (64 rows, rt 0..3);
    // k = hs*64 + ks*32 + quad*8. f32 loads + cvt (same rounding as prep_z).
    half8 af[4][4][2];
    #pragma unroll
    for (int rt = 0; rt < 4; ++rt) {
        const int row = m0 + rg * 64 + rt * 16 + lane16;
        const float* zr = gr + (size_t)row * 128 + quad * 8;
        const float* zi = gi + (size_t)row * 128 + quad * 8;
        #pragma unroll
        for (int hs = 0; hs < 4; ++hs)
            #pragma unroll
            for (int ks = 0; ks < 2; ++ks) {
                const int kb = hs * 64 + ks * 32;        // 0..224, static
                const float* p = (kb < 128) ? (zr + kb) : (zi + (kb - 128));
                float4 lo = *(const float4*)p;
                float4 hi = *(const float4*)(p + 4);
                half8 hf;
                hf[0] = (_Float16)lo.x; hf[1] = (_Float16)lo.y;
                hf[2] = (_Float16)lo.z; hf[3] = (_Float16)lo.w;
                hf[4] = (_Float16)hi.x; hf[5] = (_Float16)hi.y;
                hf[6] = (_Float16)hi.z; hf[7] = (_Float16)hi.w;
                af[rt][hs][ks] = hf;
            }
    }

    // ---- staging (phase p = 32 KB: g=p>>1, k-half h0=(p&1)*2; 4 sub-slices
    // [hh][c] of 8 KB = [64 cols][128 B of k]) ----
    // Wave stages cols [wave*8,+8) of each sub-slice = 1 gll16 (1 KB).
    // Lane L: col8=L>>3, phys chunk L&7, fetch LOGICAL chunk (L&7)^(L>>3) so
    // the XOR'd reader sees B[col][k] (R7-R9-proven, conflict-light).
    const int l3 = lane >> 3, l7 = lane & 7;
    const _Float16* pbase = B + (size_t)(wave * 8 + l3) * 256 + (l7 ^ l3) * 8;
    auto STAGE4 = [&](int p, int set) {         // set static at call sites
        const int h0 = (p & 1) * 2;
        const _Float16* sg = pbase + ((size_t)(p >> 1) << 15) + h0 * 64;
        #pragma unroll
        for (int hh = 0; hh < 2; ++hh)
            #pragma unroll
            for (int c = 0; c < 2; ++c)
                gll16(sg + hh * 64 + (size_t)c * 16384,
                      lds + set * 32768 + (hh * 2 + c) * 8192 + wave * 1024);
    };

    // fragment ds_read: wave's 32 cols live in sub-slice c = cg>>1 at
    // col_local = (cg&1)*32 + ct*16 + lane16; byte = col_local*128
    // + ((ks*4+quad) ^ (lane16&7))*16.
    uint32_t cq[2];
    #pragma unroll
    for (int ks = 0; ks < 2; ++ks)
        cq[ks] = (uint32_t)(((ks * 4 + quad) ^ (lane16 & 7)) * 16);
    const uint32_t frb = (uint32_t)((cg & 1) * 32 + lane16) * 128;
    const int csub = cg >> 1;

    // compute phase (set, h0 static): 8 ds_read_b128 + 32-MFMA prio cluster
    auto COMPUTE = [&](int set, int h0, floatx4 (&acc)[4][2]) {
        __builtin_amdgcn_s_setprio(1);
        #pragma unroll
        for (int hh = 0; hh < 2; ++hh) {
            const char* cur = lds + set * 32768 + (hh * 2 + csub) * 8192;
            half8 bf[2][2];
            #pragma unroll
            for (int ct = 0; ct < 2; ++ct)
                #pragma unroll
                for (int ks = 0; ks < 2; ++ks)
                    bf[ct][ks] = *(const half8*)(cur + frb + ct * 2048 + cq[ks]);
            #pragma unroll
            for (int ks = 0; ks < 2; ++ks)
                #pragma unroll
                for (int rt = 0; rt < 4; ++rt)
                    #pragma unroll
                    for (int ct = 0; ct < 2; ++ct)
                        acc[rt][ct] = __builtin_amdgcn_mfma_f32_16x16x32_f16(
                            af[rt][h0 + hh][ks], bf[ct][ks], acc[rt][ct], 0, 0, 0);
        }
        __builtin_amdgcn_s_setprio(0);
    };

    // packed top-2 state: [rt][r] = {p1,p2}, p = (flip(s)&~1023)|(1023-col10)
    uint32_t t2p[4][4][2];
    #pragma unroll
    for (int rt = 0; rt < 4; ++rt)
        #pragma unroll
        for (int r = 0; r < 4; ++r) {
            t2p[rt][r][0] = PACK_INIT; t2p[rt][r][1] = PACK_INIT;
        }

    float cnc[2], cnn[2], cnn2[2];
    {
        const float* c0 = cnorm + cg * 32 + lane16;
        cnc[0] = c0[0]; cnc[1] = c0[16];
    }

    auto ACCINIT = [&](floatx4 (&acc)[4][2]) {
        #pragma unroll
        for (int ct = 0; ct < 2; ++ct) {
            float v = -cnc[ct];
            floatx4 iv = (floatx4){v, v, v, v};
            #pragma unroll
            for (int rt = 0; rt < 4; ++rt) acc[rt][ct] = iv;
        }
    };

    // packed streaming top-2 (C/D: col=lane&15, row=quad*4+r). Exact
    // bit-level smaller-index tie-break via inverted col10 in low bits.
    auto TOP2 = [&](int g, floatx4 (&acc)[4][2]) {
        const uint32_t invb = 1023u - (uint32_t)(((g & 7) << 7) + cg * 32 + lane16);
        #pragma unroll
        for (int rt = 0; rt < 4; ++rt)
            #pragma unroll
            for (int r = 0; r < 4; ++r) {
                uint32_t& p1 = t2p[rt][r][0];
                uint32_t& p2 = t2p[rt][r][1];
                #pragma unroll
                for (int ct = 0; ct < 2; ++ct) {
                    uint32_t pb = fflip(__float_as_uint(acc[rt][ct][r]));
                    uint32_t p  = (pb & 0xFFFFFC00u) | (invb - ct * 16);
                    uint32_t n2 = min(max(p, p2), p1);
                    p1 = max(p, p1);
                    p2 = n2;
                }
            }
    };

    // flush every 8 g: butterfly on packs, unpack -> topbuf[row][cg], lgkm
    // barrier, tid<128 merges 4 col-groups -> part store, lgkm barrier.
    // Stores enter vmcnt: later counted syncs over-drain loads only (safe).
    auto FLUSH = [&](int slot) {
        #pragma unroll
        for (int rt = 0; rt < 4; ++rt)
            #pragma unroll
            for (int r = 0; r < 4; ++r) {
                uint32_t p1 = t2p[rt][r][0], p2 = t2p[rt][r][1];
                #pragma unroll
                for (int m = 1; m < 16; m <<= 1) {
                    uint32_t o1 = __shfl_xor((int)p1, m);
                    uint32_t o2 = __shfl_xor((int)p2, m);
                    uint32_t n1 = max(p1, o1);
                    uint32_t n2 = max(min(p1, o1), max(p2, o2));
                    p1 = n1; p2 = n2;
                }
                if (lane16 == 0) {
                    int c1 = slot * 1024 + 1023 - (int)(p1 & 1023u);
                    int c2 = slot * 1024 + 1023 - (int)(p2 & 1023u);
                    float s1 = __uint_as_float(funflip(p1 & 0xFFFFFC00u));
                    float s2 = __uint_as_float(funflip(p2 & 0xFFFFFC00u));
                    int rowl = rg * 64 + rt * 16 + quad * 4 + r;   // 0..127
                    topbuf[rowl * 4 + cg] =
                        make_float4(s1, __int_as_float(c1),
                                    s2, __int_as_float(c2));
                }
                t2p[rt][r][0] = PACK_INIT; t2p[rt][r][1] = PACK_INIT;
            }
        LGKM_BARRIER();
        if (tid < 128) {
            float4 e0 = topbuf[tid * 4 + 0], e1 = topbuf[tid * 4 + 1];
            float4 e2 = topbuf[tid * 4 + 2], e3 = topbuf[tid * 4 + 3];
            Top2 a{e0.x, __float_as_int(e0.y), e0.z, __float_as_int(e0.w)};
            Top2 b{e1.x, __float_as_int(e1.y), e1.z, __float_as_int(e1.w)};
            Top2 c{e2.x, __float_as_int(e2.y), e2.z, __float_as_int(e2.w)};
            Top2 d{e3.x, __float_as_int(e3.y), e3.z, __float_as_int(e3.w)};
            Top2 t = merge2(merge2(merge2(a, b), c), d);
            part[(size_t)(m0 + tid) * 8 + slot] =
                make_float4(t.s1, __int_as_float(t.i1),
                            t.s2, __int_as_float(t.i2));
        }
        LGKM_BARRIER();
    };

    // prologue: af + cn(0) first, PINNED before staging (issue order matters
    // for the counted ledger), then phases 0,1,2; sync(8) retires af+cn+
    // stage(0), leaves {stage(1), stage(2)} = the steady invariant.
    __builtin_amdgcn_sched_barrier(0);
    STAGE4(0, 0); STAGE4(1, 1); STAGE4(2, 2);
    PIPE_SYNC(8);

    // main loop g = 0..61 in pairs (t = g>>1) so set = phase&3 is static.
    // Even phase p=2g: [cn prefetch] stage p+3; compute set (2gs); sync(8).
    // Odd  phase p=2g+1: stage p+4; compute set (2gs+1); sync(8).
    for (int t = 0; t < 31; ++t) {
        #pragma unroll
        for (int gs = 0; gs < 2; ++gs) {
            const int g = 2 * t + gs;
            floatx4 acc[4][2];
            ACCINIT(acc);
            const int p0 = g * 2;               // p0&3 == 2*gs
            {   // cn(g+1) -> regs (compiler guards use; ledger: retires by
                // next phase's sync, shown safe for oldest-first retirement)
                const float* c1 = cnorm + (size_t)(g + 1) * 128
                                + cg * 32 + lane16;
                cnn[0] = c1[0]; cnn[1] = c1[16];
            }
            STAGE4(p0 + 3, (2 * gs + 3) & 3);
            COMPUTE(2 * gs, 0, acc);
            PIPE_SYNC(8);
            if (t == 30 && gs == 1) {           // cn(63) early (tail ledger)
                const float* c2 = cnorm + (size_t)63 * 128 + cg * 32 + lane16;
                cnn2[0] = c2[0]; cnn2[1] = c2[16];
            }
            STAGE4(p0 + 4, (2 * gs + 4) & 3);
            COMPUTE(2 * gs + 1, 2, acc);
            PIPE_SYNC(8);
            TOP2(g, acc);
            cnc[0] = cnn[0]; cnc[1] = cnn[1];
            if ((g & 7) == 7) FLUSH(g >> 3);
        }
    }
    {   // g = 62: phases 124 (set 0), 125 (set 1); stage 127 (last)
        floatx4 acc[4][2];
        ACCINIT(acc);                           // cnc = cn(62)
        STAGE4(127, 3);
        COMPUTE(0, 0, acc);
        PIPE_SYNC(8);                           // retires 125's batch
        COMPUTE(1, 2, acc);
        PIPE_SYNC(4);                           // retires 126's batch
        TOP2(62, acc);
        cnc[0] = cnn2[0]; cnc[1] = cnn2[1];
    }
    {   // g = 63: phases 126 (set 2), 127 (set 3); drain tail
        floatx4 acc[4][2];
        ACCINIT(acc);
        COMPUTE(2, 0, acc);
        PIPE_SYNC(0);                           // retires 127's batch
        COMPUTE(3, 2, acc);
        TOP2(63, acc);
        FLUSH(7);
    }
}

// ---- 3. resolve: merge 8 partials/row + WAVE-COOPERATIVE fp64 refine ----
// MARGIN 0.20 (f16-screen noise 0.12 + packed-score quantization <=2^-5 x2).
__global__ __launch_bounds__(256) void resolve(const float4* __restrict__ part,
                                               const float* __restrict__ gr,
                                               const float* __restrict__ gi,
                                               const float* __restrict__ cb,
                                               int* __restrict__ idx,
                                               float* __restrict__ out,
                                               size_t vq_off) {
    __shared__ int s_cnt;
    __shared__ int2 ent[2048];
    __shared__ double res[2048];

    const int tid = threadIdx.x;
    const int row = blockIdx.x * 256 + tid;   // grid 128
    if (blockIdx.x == 0 && tid == 0) out[vq_off] = 0.f;
    if (tid == 0) s_cnt = 0;

    float4 e[8];
    #pragma unroll
    for (int j = 0; j < 8; ++j) e[j] = part[(size_t)row * 8 + j];
    Top2 t{-3.4e38f, 0x7fffffff, -3.4e38f, 0x7fffffff};
    #pragma unroll
    for (int j = 0; j < 8; ++j) {
        Top2 o{e[j].x, __float_as_int(e[j].y), e[j].z, __float_as_int(e[j].w)};
        t = merge2(t, o);
    }
    int best = t.i1;
    const float MARGIN = 0.20f;
    const float cut = t.s1 - MARGIN;
    const bool need = (t.s1 - t.s2 < MARGIN);
    __syncthreads();              // s_cnt initialized

    int nc = 0;
    if (need) {
        #pragma unroll
        for (int j = 0; j < 8; ++j)
            #pragma unroll
            for (int c = 0; c < 2; ++c) {
                float sv = c ? e[j].z : e[j].x;
                int   ci = __float_as_int(c ? e[j].w : e[j].y);
                nc += (sv >= cut && (unsigned)ci < 8192u) ? 1 : 0;
            }
    }
    int mybase = 0;
    bool serial = false;
    if (nc) {
        mybase = atomicAdd(&s_cnt, nc);
        if (mybase + nc <= 2048) {
            int k = 0;
            #pragma unroll
            for (int j = 0; j < 8; ++j)
                #pragma unroll
                for (int c = 0; c < 2; ++c) {
                    float sv = c ? e[j].z : e[j].x;
                    int   ci = __float_as_int(c ? e[j].w : e[j].y);
                    if (sv >= cut && (unsigned)ci < 8192u)
                        ent[mybase + (k++)] = make_int2(row, ci);
                }
        } else serial = true;     // overflow fallback (needs >8 cands/row avg)
    }
    __syncthreads();
    const int cnt = (s_cnt < 2048) ? s_cnt : 2048;
    const int wave = tid >> 6, lane = tid & 63;
    for (int ee = wave; ee < cnt; ee += 4) {
        int2 rc = ent[ee];
        float4 c4 = ((const float4*)(cb + (size_t)rc.y * 256))[lane];
        float4 z4 = (lane < 32)
                  ? ((const float4*)(gr + (size_t)rc.x * 128))[lane]
                  : ((const float4*)(gi + (size_t)rc.x * 128))[lane - 32];
        double dx = (double)z4.x - (double)c4.x;
        double dy = (double)z4.y - (double)c4.y;
        double dz = (double)z4.z - (double)c4.z;
        double dw = (double)z4.w - (double)c4.w;
        double d = dx * dx + dy * dy + dz * dz + dw * dw;
        #pragma unroll
        for (int m = 1; m < 64; m <<= 1) d += __shfl_xor(d, m);
        if (lane == 0) res[ee] = d;
    }
    __syncthreads();
    if (nc && !serial) {
        double bd = 1e300; int bi = 0x7fffffff;
        for (int k = 0; k < nc; ++k) {
            double d = res[mybase + k];
            int   ci = ent[mybase + k].y;
            if (d < bd || (d == bd && ci < bi)) { bd = d; bi = ci; }
        }
        if ((unsigned)bi < 8192u) best = bi;
    } else if (serial) {          // overflow fallback (rare)
        double bd = 1e300; int bi = 0x7fffffff;
        const float* zr = gr + (size_t)row * 128;
        const float* zi = gi + (size_t)row * 128;
        #pragma unroll
        for (int j = 0; j < 8; ++j)
            #pragma unroll
            for (int c = 0; c < 2; ++c) {
                float sv = c ? e[j].z : e[j].x;
                int   ci = __float_as_int(c ? e[j].w : e[j].y);
                if (sv >= cut && (unsigned)ci < 8192u) {
                    const float* crow = cb + (size_t)ci * 256;
                    double d = 0.0;
                    for (int k = 0; k < 128; ++k) {
                        double a = (double)zr[k] - (double)crow[k];
                        double b = (double)zi[k] - (double)crow[128 + k];
                        d += a * a + b * b;
                    }
                    if (d < bd || (d == bd && ci < bi)) { bd = d; bi = ci; }
                }
            }
        if ((unsigned)bi < 8192u) best = bi;
    }
    idx[row] = ((unsigned)best < 8192u) ? best : 0;
}

// ---- 4. gather + proposal(REAL part only) + salience + vq (one wave/row) ----
__global__ __launch_bounds__(256) void gather_epi(const int* __restrict__ idx,
                                                  const float* __restrict__ gr,
                                                  const float* __restrict__ gi,
                                                  const float* __restrict__ cb,
                                                  const float* __restrict__ salw,
                                                  const float* __restrict__ salb,
                                                  float* __restrict__ out,
                                                  size_t sal_off, size_t vq_off) {
    const int wave = threadIdx.x >> 6, lane = threadIdx.x & 63;
    const int row = blockIdx.x * 4 + wave;
    int id = idx[row];
    if ((unsigned)id >= 8192u) id = 0;   // clamp: no wild reads

    float4 c4 = ((const float4*)(cb + (size_t)id * 256))[lane];
    float4 z4 = (lane < 32) ? ((const float4*)(gr + (size_t)row * 128))[lane]
                            : ((const float4*)(gi + (size_t)row * 128))[lane - 32];

    float dx = c4.x - z4.x, dy = c4.y - z4.y, dz = c4.z - z4.z, dw = c4.w - z4.w;
    float vq = dx * dx + dy * dy + dz * dz + dw * dw;
    float4 w4 = ((const float4*)salw)[lane];
    float sal = c4.x * w4.x + c4.y * w4.y + c4.z * w4.z + c4.w * w4.w;
    #pragma unroll
    for (int m = 1; m < 64; m <<= 1) {
        vq  += __shfl_xor(vq, m);
        sal += __shfl_xor(sal, m);
    }

    // proposal: real part only — lanes 0..31 hold c[0..128) as float4s
    if (lane < 32 && (size_t)(row + 1) * 128 <= sal_off) {
        float4* op = (float4*)(out + (size_t)row * 128);
        op[lane] = c4;
    }
    if (lane == 0 && sal_off + row < vq_off)
        out[sal_off + row] = sal + salb[0];

    __shared__ float vqs[4];
    if (lane == 0) vqs[wave] = vq;
    __syncthreads();
    if (threadIdx.x == 0) {
        float p = (vqs[0] + vqs[1] + vqs[2] + vqs[3]) * (1.25f / 8388608.f);
        atomicAdd(out + vq_off, p);
    }
}

extern "C" void kernel_launch(void* const* d_in, const int* in_sizes, int n_in,
                              void* d_out, int out_size, void* d_ws, size_t ws_size,
                              hipStream_t stream) {
    const float* gr = (const float*)d_in[0];   // gw_real  [8,4096,128]
    const float* gi = (const float*)d_in[1];   // gw_imag  [8,4096,128]
    const float* cb = (const float*)d_in[2];   // codebook [8192,256]
    const float* sw = (const float*)d_in[3];   // sal_w    [1,256]
    const float* sb = (const float*)d_in[4];   // sal_b    [1]
    float* out = (float*)d_out;

    // Output offsets (out_size = 4,227,073 floats:
    // proposal-real 4,194,304 | salience 32,768 | vq_loss 1).
    size_t vq_off  = (size_t)out_size - 1;
    size_t sal_off = (size_t)out_size - 1 - 32768;

    char* base = (char*)d_ws;
    int*  idxb = (int*)(base + IDX_OFF);
    _Float16* Bq   = (_Float16*)(base + B_OFF);
    float*    cn   = (float*)   (base + CN_OFF);
    float4*   part = (float4*)  (base + PART_OFF);

    prep_c<<<2048, 256, 0, stream>>>(cb, Bq, cn);
    gemm_argmin<<<256, 512, 0, stream>>>(gr, gi, Bq, cn, part);
    resolve<<<128, 256, 0, stream>>>(part, gr, gi, cb, idxb, out, vq_off);
    gather_epi<<<8192, 256, 0, stream>>>(idxb, gr, gi, cb, sw, sb, out,
                                         sal_off, vq_off);
}

// Round 13
// 295.518 us; speedup vs baseline: 1.4660x; 1.4660x over previous
//
#include <hip/hip_runtime.h>
#include <stdint.h>

// Problem constants
#define MROWS 32768      // B*S = 8*4096
#define KD    256        // 2*DIM
#define VOCABN 8192

typedef _Float16 half8  __attribute__((ext_vector_type(8)));
typedef _Float16 half4v __attribute__((ext_vector_type(4)));
typedef float  floatx4  __attribute__((ext_vector_type(4)));

// scratch layout (byte offsets within d_ws)
#define VQP_OFF   0u          // f32 vq partials [8192] = 32 KB (A region free)
#define B_OFF     16777216u   // f16 cb [8192][256]   =  4,194,304 B
#define CN_OFF    20971520u   // f32 0.5*||c||^2 [8192] = 32,768 B
#define PART_OFF  21004288u   // float4 top2 [32768][8] = 4,194,304 B
#define IDX_OFF   25198592u   // int idx [32768] = 131,072 B
#define WS_NEED   25329664u

// ---- top-2 (max sigma) with smaller-index tie-break (merge/resolve path) ----
struct Top2 { float s1; int i1; float s2; int i2; };

__device__ __forceinline__ bool better(float sa, int ia, float sb, int ib) {
    return (sa > sb) || (sa == sb && ia < ib);
}
__device__ __forceinline__ Top2 merge2(const Top2& a, const Top2& b) {
    Top2 r;
    if (better(b.s1, b.i1, a.s1, a.i1)) {
        r.s1 = b.s1; r.i1 = b.i1;
        if (better(a.s1, a.i1, b.s2, b.i2)) { r.s2 = a.s1; r.i2 = a.i1; }
        else                                { r.s2 = b.s2; r.i2 = b.i2; }
    } else {
        r.s1 = a.s1; r.i1 = a.i1;
        if (better(b.s1, b.i1, a.s2, a.i2)) { r.s2 = b.s1; r.i2 = b.i1; }
        else                                { r.s2 = a.s2; r.i2 = a.i2; }
    }
    return r;
}

// monotone f32<->u32 order-preserving flip (for packed top-2)
__device__ __forceinline__ uint32_t fflip(uint32_t u) {
    return u ^ (0x80000000u | (uint32_t)((int32_t)u >> 31));
}
__device__ __forceinline__ uint32_t funflip(uint32_t v) {
    return v ^ (0x80000000u | (uint32_t)((int32_t)(~v) >> 31));
}
// sentinel: pack of (-3.4e38f, col10=1023) == 0x00800000
#define PACK_INIT 0x00800000u

// async global->LDS, 16 B per lane. LDS dest is WAVE-UNIFORM base + lane*16;
// global src is per-lane (swizzle is applied by pre-permuting the src).
__device__ __forceinline__ void gll16(const void* g, const void* l) {
    __builtin_amdgcn_global_load_lds(
        (const __attribute__((address_space(1))) void*)g,
        (__attribute__((address_space(3))) void*)l, 16, 0, 0);
}

// counted-vmcnt pipe barrier (T3/T4): drain to N outstanding, raw s_barrier.
#define PIPE_SYNC(N) do {                                        \
    asm volatile("s_waitcnt vmcnt(" #N ")" ::: "memory");        \
    __builtin_amdgcn_s_barrier();                                \
    __builtin_amdgcn_sched_barrier(0);                           \
} while (0)

// lgkm-only barrier (flush path): staged vmcnt loads stay in flight.
#define LGKM_BARRIER() do {                                      \
    asm volatile("s_waitcnt lgkmcnt(0)" ::: "memory");           \
    __builtin_amdgcn_s_barrier();                                \
    __builtin_amdgcn_sched_barrier(0);                           \
} while (0)

// ---- 1. codebook f16 [8192][256] + 0.5*||c||^2 fp32 (4 rows/block) ----
__global__ __launch_bounds__(256) void prep_c(const float* __restrict__ cb,
                                              _Float16* __restrict__ B,
                                              float* __restrict__ cnorm) {
    int v = blockIdx.x * 4 + (threadIdx.x >> 6);
    int lane = threadIdx.x & 63;               // 0..63, 4 floats each
    float4 c = ((const float4*)(cb + (size_t)v * 256))[lane];
    half4v h;
    h[0] = (_Float16)c.x; h[1] = (_Float16)c.y;
    h[2] = (_Float16)c.z; h[3] = (_Float16)c.w;
    ((half4v*)(B + (size_t)v * 256))[lane] = h;
    float s = c.x * c.x + c.y * c.y + c.z * c.z + c.w * c.w;
    #pragma unroll
    for (int m = 32; m; m >>= 1) s += __shfl_xor(s, m);
    if (lane == 0) cnorm[v] = 0.5f * s;
}

// ---- 2. f16 GEMM + per-row top-2 argmax(sigma) ----
// R27/R26 post-mortem: BOTH launch_bounds(512,1) and amdgpu_waves_per_eu(2,2)
// produced byte-identical codegen (VGPR 128, 59MB spill writes) -- this
// toolchain will NOT give the kernel >128 arch VGPRs. Hard constraint:
// structure must FIT 128 arch VGPRs (acc in AGPRs). R28 = the R24 structure
// (Round-9-proven: VGPR 128, WRITE 11MB = part-only, gemm 226us -- best
// measured), with ONE change: grid 512 -> 256, whole vocab per block (no nh;
// g 0..62 + peeled 63; FLUSH slot g>>3). Phase-set parity set=ph is
// g-independent, so the loop body is byte-identical to R24's. Removes the
// duplicate af load + second sequential block round. Per-phase: 4 ds_read_
// b128 + 16-MFMA setprio cluster, STAGE2(p+3) depth-3, PIPE_SYNC(4).
__global__ __launch_bounds__(512, 2) void gemm_argmin(const float* __restrict__ gr,
                                                      const float* __restrict__ gi,
                                                      const _Float16* __restrict__ B,
                                                      const float* __restrict__ cnorm,
                                                      float4* __restrict__ part) {
    // LDS: 8 x 8 KB sub-slice buffers (4 sets x {c0,c1}) | 8 KB topbuf = 72 KB
    __shared__ __align__(16) char lds[73728];
    float4* topbuf = (float4*)(lds + 65536);   // [128 rows][4 cg]

    const int tid = threadIdx.x;
    const int m0 = blockIdx.x * 128;            // grid 256
    const int wave = tid >> 6, lane = tid & 63;
    const int rg = wave >> 2, cg = wave & 3;    // 2 row-groups x 4 col-groups
    const int lane16 = lane & 15, quad = lane >> 4;

    // A-fragments: wave owns rows m0+rg*64+rt*16+lane16 (64 rows, rt 0..3);
    // k = hs*64 + ks*32 + quad*8. f32 loads + cvt (same rounding as prep_z).
    // af[4][4][2] = 32 half8 = 128 VGPR, register-resident.
    half8 af[4][4][2];
    #pragma unroll
    for (int rt = 0; rt < 4; ++rt) {
        const int row = m0 + rg * 64 + rt * 16 + lane16;
        const float* zr = gr + (size_t)row * 128 + quad * 8;
        const float* zi = gi + (size_t)row * 128 + quad * 8;
        #pragma unroll
        for (int hs = 0; hs < 4; ++hs)
            #pragma unroll
            for (int ks = 0; ks < 2; ++ks) {
                const int kb = hs * 64 + ks * 32;        // 0..224, static
                const float* p = (kb < 128) ? (zr + kb) : (zi + (kb - 128));
                float4 lo = *(const float4*)p;
                float4 hi = *(const float4*)(p + 4);
                half8 hf;
                hf[0] = (_Float16)lo.x; hf[1] = (_Float16)lo.y;
                hf[2] = (_Float16)lo.z; hf[3] = (_Float16)lo.w;
                hf[4] = (_Float16)hi.x; hf[5] = (_Float16)hi.y;
                hf[6] = (_Float16)hi.z; hf[7] = (_Float16)hi.w;
                af[rt][hs][ks] = hf;
            }
    }

    // ---- staging (8-KB sub-slice = [64 cols][128 B of k]) ----
    // phase p (0..255): g=p>>2, hs=p&3; sub-slices v=2p+c (c=0,1) = cols
    // g*128+c*64, k hs*64..+64. Wave stages cols [wave*8,+8) of each = 1
    // gll16/sub-slice. Lane L: col8=L>>3, phys chunk L&7, fetch LOGICAL
    // chunk (L&7)^(L>>3) so the XOR'd reader sees B[col][k] (proven).
    const int l3 = lane >> 3, l7 = lane & 7;
    const _Float16* pbase = B + (size_t)(wave * 8 + l3) * 256 + (l7 ^ l3) * 8;
    auto STAGE2 = [&](int q, int set) {       // q = phase, set = q&3 (static)
        const _Float16* s0 = pbase + ((size_t)(q >> 2) * 128) * 256
                           + (q & 3) * 64;
        gll16(s0,             lds + (set * 2 + 0) * 8192 + wave * 1024);
        gll16(s0 + 64 * 256,  lds + (set * 2 + 1) * 8192 + wave * 1024);
    };

    // fragment ds_read: wave's 32 cols live in sub-slice c = cg>>1 at
    // col_local = (cg&1)*32 + ct*16 + lane16; byte = col_local*128
    // + ((ks*4+quad) ^ (lane16&7))*16  (proven conflict-free swizzle).
    uint32_t cq[2];
    #pragma unroll
    for (int ks = 0; ks < 2; ++ks)
        cq[ks] = (uint32_t)(((ks * 4 + quad) ^ (lane16 & 7)) * 16);
    const uint32_t frb = (uint32_t)((cg & 1) * 32 + lane16) * 128;
    const int csub = cg >> 1;                 // which sub-slice of the pair

    // compute phase (set=hs=ph static): 4 ds_read_b128 + 16 MFMA (reuse 4)
    auto COMPUTE = [&](int set, floatx4 (&acc)[4][2]) {
        const char* cur = lds + (set * 2 + csub) * 8192;
        half8 bf[2][2];
        #pragma unroll
        for (int ct = 0; ct < 2; ++ct)
            #pragma unroll
            for (int ks = 0; ks < 2; ++ks)
                bf[ct][ks] = *(const half8*)(cur + frb + ct * 2048 + cq[ks]);
        __builtin_amdgcn_s_setprio(1);
        #pragma unroll
        for (int ks = 0; ks < 2; ++ks)
            #pragma unroll
            for (int rt = 0; rt < 4; ++rt)
                #pragma unroll
                for (int ct = 0; ct < 2; ++ct)
                    acc[rt][ct] = __builtin_amdgcn_mfma_f32_16x16x32_f16(
                        af[rt][set][ks], bf[ct][ks], acc[rt][ct], 0, 0, 0);
        __builtin_amdgcn_s_setprio(0);
    };

    // packed top-2 state: [rt][r] = {p1, p2}, p = (flip(s)&~1023)|(1023-col10)
    uint32_t t2p[4][4][2];
    #pragma unroll
    for (int rt = 0; rt < 4; ++rt)
        #pragma unroll
        for (int r = 0; r < 4; ++r) {
            t2p[rt][r][0] = PACK_INIT; t2p[rt][r][1] = PACK_INIT;
        }

    // cn prefetch registers (2 cols/lane: ct=0,1)
    float cnc[2], cnn[2];
    {
        const float* c0 = cnorm + cg * 32 + lane16;
        cnc[0] = c0[0]; cnc[1] = c0[16];
    }

    auto ACCINIT = [&](floatx4 (&acc)[4][2]) {
        #pragma unroll
        for (int ct = 0; ct < 2; ++ct) {
            float v = -cnc[ct];
            floatx4 iv = (floatx4){v, v, v, v};
            #pragma unroll
            for (int rt = 0; rt < 4; ++rt) acc[rt][ct] = iv;
        }
    };

    // packed streaming top-2 (C/D: col=lane&15, row=quad*4+r). Exact
    // bit-level smaller-index tie-break via inverted col10 in low bits.
    auto TOP2 = [&](int g, floatx4 (&acc)[4][2]) {
        const uint32_t invb = 1023u - (uint32_t)(((g & 7) << 7) + cg * 32 + lane16);
        #pragma unroll
        for (int rt = 0; rt < 4; ++rt)
            #pragma unroll
            for (int r = 0; r < 4; ++r) {
                uint32_t& p1 = t2p[rt][r][0];
                uint32_t& p2 = t2p[rt][r][1];
                #pragma unroll
                for (int ct = 0; ct < 2; ++ct) {
                    uint32_t pb = fflip(__float_as_uint(acc[rt][ct][r]));
                    uint32_t p  = (pb & 0xFFFFFC00u) | (invb - ct * 16);
                    uint32_t n2 = min(max(p, p2), p1);
                    p1 = max(p, p1);
                    p2 = n2;
                }
            }
    };

    // flush every 8 g: 16-lane butterfly on packs, unpack -> topbuf[row][cg],
    // lgkm barrier, tid<128 merges 4 col-groups -> part store, lgkm barrier.
    // part store enters vmcnt: later counted syncs over-drain only (safe).
    auto FLUSH = [&](int slot) {
        #pragma unroll
        for (int rt = 0; rt < 4; ++rt)
            #pragma unroll
            for (int r = 0; r < 4; ++r) {
                uint32_t p1 = t2p[rt][r][0], p2 = t2p[rt][r][1];
                #pragma unroll
                for (int m = 1; m < 16; m <<= 1) {
                    uint32_t o1 = __shfl_xor((int)p1, m);
                    uint32_t o2 = __shfl_xor((int)p2, m);
                    uint32_t n1 = max(p1, o1);
                    uint32_t n2 = max(min(p1, o1), max(p2, o2));
                    p1 = n1; p2 = n2;
                }
                if (lane16 == 0) {
                    int c1 = slot * 1024 + 1023 - (int)(p1 & 1023u);
                    int c2 = slot * 1024 + 1023 - (int)(p2 & 1023u);
                    float s1 = __uint_as_float(funflip(p1 & 0xFFFFFC00u));
                    float s2 = __uint_as_float(funflip(p2 & 0xFFFFFC00u));
                    int rowl = rg * 64 + rt * 16 + quad * 4 + r;   // 0..127
                    topbuf[rowl * 4 + cg] =
                        make_float4(s1, __int_as_float(c1),
                                    s2, __int_as_float(c2));
                }
                t2p[rt][r][0] = PACK_INIT; t2p[rt][r][1] = PACK_INIT;
            }
        LGKM_BARRIER();
        if (tid < 128) {
            float4 e0 = topbuf[tid * 4 + 0], e1 = topbuf[tid * 4 + 1];
            float4 e2 = topbuf[tid * 4 + 2], e3 = topbuf[tid * 4 + 3];
            Top2 a{e0.x, __float_as_int(e0.y), e0.z, __float_as_int(e0.w)};
            Top2 b{e1.x, __float_as_int(e1.y), e1.z, __float_as_int(e1.w)};
            Top2 c{e2.x, __float_as_int(e2.y), e2.z, __float_as_int(e2.w)};
            Top2 d{e3.x, __float_as_int(e3.y), e3.z, __float_as_int(e3.w)};
            Top2 t = merge2(merge2(merge2(a, b), c), d);
            part[(size_t)(m0 + tid) * 8 + slot] =
                make_float4(t.s1, __int_as_float(t.i1),
                            t.s2, __int_as_float(t.i2));
        }
        LGKM_BARRIER();
    };

    // prologue: af + cn(0) loads, stage phases 0,1,2; vmcnt(4) completes
    // af+cn+stage(0), leaves {stage(1),stage(2)} -> invariant entering p=0.
    STAGE2(0, 0); STAGE2(1, 1); STAGE2(2, 2);
    PIPE_SYNC(4);

    // main loop g=0..62; phase p=g*4+ph, set=ph (g*4 % 4 == 0), stage p+3
    // into set (ph+3)&3. Ledger per g identical to the proven R24 schedule.
    for (int g = 0; g < 63; ++g) {
        floatx4 acc[4][2];
        ACCINIT(acc);
        const int p0 = g * 4;
        #pragma unroll
        for (int ph = 0; ph < 4; ++ph) {
            STAGE2(p0 + ph + 3, (ph + 3) & 3);
            if (ph == 0) {   // cn(g+1) -> regs; rides vmcnt, done by ph2 sync
                const float* c1 = cnorm + (size_t)(g + 1) * 128
                                + cg * 32 + lane16;
                cnn[0] = c1[0]; cnn[1] = c1[16];
            }
            COMPUTE(ph, acc);
            PIPE_SYNC(4);
        }
        cnc[0] = cnn[0]; cnc[1] = cnn[1];
        TOP2(g, acc);
        if ((g & 7) == 7) FLUSH(g >> 3);
    }
    {   // g = 63: phases 252..255; stage 255 at ph0, then descending drains
        floatx4 acc[4][2];
        ACCINIT(acc);
        STAGE2(255, 3); COMPUTE(0, acc); PIPE_SYNC(4);
        COMPUTE(1, acc); PIPE_SYNC(2);
        COMPUTE(2, acc); PIPE_SYNC(0);
        COMPUTE(3, acc);
        TOP2(63, acc);
        FLUSH(7);
    }
}

// ---- 3. resolve: merge 8 partials/row + WAVE-COOPERATIVE fp64 refine ----
// MARGIN 0.20 (f16-screen noise 0.12 + packed-score quantization <=2^-5 x2).
__global__ __launch_bounds__(256) void resolve(const float4* __restrict__ part,
                                               const float* __restrict__ gr,
                                               const float* __restrict__ gi,
                                               const float* __restrict__ cb,
                                               int* __restrict__ idx) {
    __shared__ int s_cnt;
    __shared__ int2 ent[2048];
    __shared__ double res[2048];

    const int tid = threadIdx.x;
    const int row = blockIdx.x * 256 + tid;   // grid 128
    if (tid == 0) s_cnt = 0;

    float4 e[8];
    #pragma unroll
    for (int j = 0; j < 8; ++j) e[j] = part[(size_t)row * 8 + j];
    Top2 t{-3.4e38f, 0x7fffffff, -3.4e38f, 0x7fffffff};
    #pragma unroll
    for (int j = 0; j < 8; ++j) {
        Top2 o{e[j].x, __float_as_int(e[j].y), e[j].z, __float_as_int(e[j].w)};
        t = merge2(t, o);
    }
    int best = t.i1;
    const float MARGIN = 0.20f;
    const float cut = t.s1 - MARGIN;
    const bool need = (t.s1 - t.s2 < MARGIN);
    __syncthreads();              // s_cnt initialized

    int nc = 0;
    if (need) {
        #pragma unroll
        for (int j = 0; j < 8; ++j)
            #pragma unroll
            for (int c = 0; c < 2; ++c) {
                float sv = c ? e[j].z : e[j].x;
                int   ci = __float_as_int(c ? e[j].w : e[j].y);
                nc += (sv >= cut && (unsigned)ci < 8192u) ? 1 : 0;
            }
    }
    int mybase = 0;
    bool serial = false;
    if (nc) {
        mybase = atomicAdd(&s_cnt, nc);
        if (mybase + nc <= 2048) {
            int k = 0;
            #pragma unroll
            for (int j = 0; j < 8; ++j)
                #pragma unroll
                for (int c = 0; c < 2; ++c) {
                    float sv = c ? e[j].z : e[j].x;
                    int   ci = __float_as_int(c ? e[j].w : e[j].y);
                    if (sv >= cut && (unsigned)ci < 8192u)
                        ent[mybase + (k++)] = make_int2(row, ci);
                }
        } else serial = true;     // overflow fallback (needs >8 cands/row avg)
    }
    __syncthreads();
    const int cnt = (s_cnt < 2048) ? s_cnt : 2048;
    const int wave = tid >> 6, lane = tid & 63;
    for (int ee = wave; ee < cnt; ee += 4) {
        int2 rc = ent[ee];
        float4 c4 = ((const float4*)(cb + (size_t)rc.y * 256))[lane];
        float4 z4 = (lane < 32)
                  ? ((const float4*)(gr + (size_t)rc.x * 128))[lane]
                  : ((const float4*)(gi + (size_t)rc.x * 128))[lane - 32];
        double dx = (double)z4.x - (double)c4.x;
        double dy = (double)z4.y - (double)c4.y;
        double dz = (double)z4.z - (double)c4.z;
        double dw = (double)z4.w - (double)c4.w;
        double d = dx * dx + dy * dy + dz * dz + dw * dw;
        #pragma unroll
        for (int m = 1; m < 64; m <<= 1) d += __shfl_xor(d, m);
        if (lane == 0) res[ee] = d;
    }
    __syncthreads();
    if (nc && !serial) {
        double bd = 1e300; int bi = 0x7fffffff;
        for (int k = 0; k < nc; ++k) {
            double d = res[mybase + k];
            int   ci = ent[mybase + k].y;
            if (d < bd || (d == bd && ci < bi)) { bd = d; bi = ci; }
        }
        if ((unsigned)bi < 8192u) best = bi;
    } else if (serial) {          // overflow fallback (rare)
        double bd = 1e300; int bi = 0x7fffffff;
        const float* zr = gr + (size_t)row * 128;
        const float* zi = gi + (size_t)row * 128;
        #pragma unroll
        for (int j = 0; j < 8; ++j)
            #pragma unroll
            for (int c = 0; c < 2; ++c) {
                float sv = c ? e[j].z : e[j].x;
                int   ci = __float_as_int(c ? e[j].w : e[j].y);
                if (sv >= cut && (unsigned)ci < 8192u) {
                    const float* crow = cb + (size_t)ci * 256;
                    double d = 0.0;
                    for (int k = 0; k < 128; ++k) {
                        double a = (double)zr[k] - (double)crow[k];
                        double b = (double)zi[k] - (double)crow[128 + k];
                        d += a * a + b * b;
                    }
                    if (d < bd || (d == bd && ci < bi)) { bd = d; bi = ci; }
                }
            }
        if ((unsigned)bi < 8192u) best = bi;
    }
    idx[row] = ((unsigned)best < 8192u) ? best : 0;
}

// ---- 4. gather + proposal(REAL part only) + salience + vq partial ----
// R28: the 8192 same-address atomicAdd(out+vq_off) serialized through one
// L2 slice (~25cy each ~ 85us -- the hidden bulk of the ~180us non-gemm
// time). Now: per-block partial -> vqpart[block]; vq_reduce sums them.
__global__ __launch_bounds__(256) void gather_epi(const int* __restrict__ idx,
                                                  const float* __restrict__ gr,
                                                  const float* __restrict__ gi,
                                                  const float* __restrict__ cb,
                                                  const float* __restrict__ salw,
                                                  const float* __restrict__ salb,
                                                  float* __restrict__ out,
                                                  float* __restrict__ vqpart,
                                                  size_t sal_off, size_t vq_off) {
    const int wave = threadIdx.x >> 6, lane = threadIdx.x & 63;
    const int row = blockIdx.x * 4 + wave;
    int id = idx[row];
    if ((unsigned)id >= 8192u) id = 0;   // clamp: no wild reads

    float4 c4 = ((const float4*)(cb + (size_t)id * 256))[lane];
    float4 z4 = (lane < 32) ? ((const float4*)(gr + (size_t)row * 128))[lane]
                            : ((const float4*)(gi + (size_t)row * 128))[lane - 32];

    float dx = c4.x - z4.x, dy = c4.y - z4.y, dz = c4.z - z4.z, dw = c4.w - z4.w;
    float vq = dx * dx + dy * dy + dz * dz + dw * dw;
    float4 w4 = ((const float4*)salw)[lane];
    float sal = c4.x * w4.x + c4.y * w4.y + c4.z * w4.z + c4.w * w4.w;
    #pragma unroll
    for (int m = 1; m < 64; m <<= 1) {
        vq  += __shfl_xor(vq, m);
        sal += __shfl_xor(sal, m);
    }

    // proposal: real part only — lanes 0..31 hold c[0..128) as float4s
    if (lane < 32 && (size_t)(row + 1) * 128 <= sal_off) {
        float4* op = (float4*)(out + (size_t)row * 128);
        op[lane] = c4;
    }
    if (lane == 0 && sal_off + row < vq_off)
        out[sal_off + row] = sal + salb[0];

    __shared__ float vqs[4];
    if (lane == 0) vqs[wave] = vq;
    __syncthreads();
    if (threadIdx.x == 0)
        vqpart[blockIdx.x] = vqs[0] + vqs[1] + vqs[2] + vqs[3];
}

// ---- 5. vq_reduce: sum 8192 partials -> vq_loss (one block, no atomics) ----
__global__ __launch_bounds__(256) void vq_reduce(const float* __restrict__ vqpart,
                                                 float* __restrict__ out,
                                                 size_t vq_off) {
    const int tid = threadIdx.x;
    float s = 0.f;
    #pragma unroll
    for (int j = 0; j < 32; ++j) s += vqpart[tid + j * 256];
    #pragma unroll
    for (int m = 1; m < 64; m <<= 1) s += __shfl_xor(s, m);
    __shared__ float ws[4];
    if ((tid & 63) == 0) ws[tid >> 6] = s;
    __syncthreads();
    if (tid == 0)
        out[vq_off] = (ws[0] + ws[1] + ws[2] + ws[3]) * (1.25f / 8388608.f);
}

extern "C" void kernel_launch(void* const* d_in, const int* in_sizes, int n_in,
                              void* d_out, int out_size, void* d_ws, size_t ws_size,
                              hipStream_t stream) {
    const float* gr = (const float*)d_in[0];   // gw_real  [8,4096,128]
    const float* gi = (const float*)d_in[1];   // gw_imag  [8,4096,128]
    const float* cb = (const float*)d_in[2];   // codebook [8192,256]
    const float* sw = (const float*)d_in[3];   // sal_w    [1,256]
    const float* sb = (const float*)d_in[4];   // sal_b    [1]
    float* out = (float*)d_out;

    // Output offsets (out_size = 4,227,073 floats:
    // proposal-real 4,194,304 | salience 32,768 | vq_loss 1).
    size_t vq_off  = (size_t)out_size - 1;
    size_t sal_off = (size_t)out_size - 1 - 32768;

    char* base = (char*)d_ws;
    int*  idxb = (int*)(base + IDX_OFF);
    float*    vqp  = (float*)   (base + VQP_OFF);
    _Float16* Bq   = (_Float16*)(base + B_OFF);
    float*    cn   = (float*)   (base + CN_OFF);
    float4*   part = (float4*)  (base + PART_OFF);

    prep_c<<<2048, 256, 0, stream>>>(cb, Bq, cn);
    gemm_argmin<<<256, 512, 0, stream>>>(gr, gi, Bq, cn, part);
    resolve<<<128, 256, 0, stream>>>(part, gr, gi, cb, idxb);
    gather_epi<<<8192, 256, 0, stream>>>(idxb, gr, gi, cb, sw, sb, out, vqp,
                                         sal_off, vq_off);
    vq_reduce<<<1, 256, 0, stream>>>(vqp, out, vq_off);
}